// Round 4
// baseline (43.370 us; speedup 1.0000x reference)
//
#include <hip/hip_runtime.h>

// Fused: 2x2x2 max-pool (stride 2) + per-channel bias + logsumexp over C=64 + ReLU.
// DTYPE FINDING (R1/R2/R3 error-magnitude forensics): the harness upcasts the
// reference's fp16 inputs to FLOAT32 on device (fp16-upcast f32 => low 13
// mantissa bits zero; reading them as bf16 pairs yields garbage set {±2^-63,
// ±2, ±2^65} -> R2's exact 2^66 absmax; as fp16 pairs {±0.0078, ±2, ±512} ->
// R1's 1018.66 and R3's 510.66). So: x = const float* [4,64,64,64,64],
// bias = const float* [64], out = float* [4,1,32,32,32].
//
// Decomposition: each output voxel owned by a lane PAIR (i, i+32): half 0 does
// channels 0..31, half 1 channels 32..63; merge (m,s) via one __shfl_xor(.,32).
// 4096 waves = 16/CU. float2 loads (8 B/lane, 256 B/segment) -> coalesced,
// input read exactly once (268.4 MB -> ~43 us roofline @ 6.3 TB/s).

__global__ __launch_bounds__(256) void fused_pool_lse_relu(
    const float* __restrict__ x, const float* __restrict__ bias,
    float* __restrict__ out)
{
    __shared__ float s_bias[64];
    if (threadIdx.x < 64) s_bias[threadIdx.x] = bias[threadIdx.x];
    __syncthreads();

    const int lane  = threadIdx.x & 63;
    const int wave  = threadIdx.x >> 6;
    const int chalf = lane >> 5;                        // 0: c=0..31, 1: c=32..63
    const int o     = blockIdx.x * 128 + wave * 32 + (lane & 31);

    const int wp = o & 31;          // output w'
    const int hp = (o >> 5) & 31;   // output h'
    const int dp = (o >> 10) & 31;  // output d'
    const int n  = o >> 15;         // batch

    // element strides (f32): w:1, h:64, d:4096, c:262144, n:64*262144
    const size_t CS = 262144;
    const float* base = x
        + (size_t)n * (64 * CS)
        + (size_t)(chalf * 32) * CS
        + (size_t)dp * 8192        // 2*dp*4096
        + (size_t)hp * 128         // 2*hp*64
        + (size_t)wp * 2;

    float vals[32];
#pragma unroll
    for (int cc = 0; cc < 32; ++cc) {
        const float* p = base + (size_t)cc * CS;
        const float2 a = *(const float2*)(p);          // d0,h0 (w0,w1)
        const float2 b = *(const float2*)(p + 64);     // d0,h1
        const float2 c = *(const float2*)(p + 4096);   // d1,h0
        const float2 d = *(const float2*)(p + 4160);   // d1,h1
        const float v = fmaxf(fmaxf(fmaxf(a.x, a.y), fmaxf(b.x, b.y)),
                              fmaxf(fmaxf(c.x, c.y), fmaxf(d.x, d.y)));
        vals[cc] = v + s_bias[chalf * 32 + cc];
    }

    // two-pass logsumexp over this lane's 32 channels (all indices static)
    float m = vals[0];
#pragma unroll
    for (int cc = 1; cc < 32; ++cc) m = fmaxf(m, vals[cc]);
    float s = 0.0f;
#pragma unroll
    for (int cc = 0; cc < 32; ++cc) s += __expf(vals[cc] - m);

    // merge the two channel-halves across the lane pair
    const float m2 = __shfl_xor(m, 32);
    const float s2 = __shfl_xor(s, 32);
    const float M  = fmaxf(m, m2);
    const float st = s * __expf(m - M) + s2 * __expf(m2 - M);
    const float r  = fmaxf(M + __logf(st), 0.0f);   // ReLU

    if (chalf == 0) out[o] = r;
}

extern "C" void kernel_launch(void* const* d_in, const int* in_sizes, int n_in,
                              void* d_out, int out_size, void* d_ws, size_t ws_size,
                              hipStream_t stream)
{
    const float* x    = (const float*)d_in[0];
    const float* bias = (const float*)d_in[1];
    float* out = (float*)d_out;

    // out_size = 4*32*32*32 = 131072; each block covers 128 outputs
    const int blocks = out_size / 128;   // 1024
    fused_pool_lse_relu<<<blocks, 256, 0, stream>>>(x, bias, out);
}